// Round 5
// baseline (458.634 us; speedup 1.0000x reference)
//
#include <hip/hip_runtime.h>

#define BN_EPS 1e-5f
#define CAP 3072   // per-bucket edge capacity (mean 1805, +30 sigma; guarded)

using bf16x8 = __attribute__((ext_vector_type(8))) short;
using f32x4  = __attribute__((ext_vector_type(4))) float;

__device__ __forceinline__ unsigned int f2bf(float f) {   // RTNE fp32->bf16
    unsigned int u = __float_as_uint(f);
    u += 0x7fffu + ((u >> 16) & 1u);
    return u >> 16;
}
// packed RTNE fp32x2 -> bf16x2 (bit-identical to f2bf pair)
__device__ __forceinline__ unsigned int f2bf2(float lo, float hi) {
    unsigned int r;
    asm("v_cvt_pk_bf16_f32 %0, %1, %2" : "=v"(r) : "v"(lo), "v"(hi));
    return r;
}
__device__ __forceinline__ float bflo(unsigned int u) { return __uint_as_float(u << 16); }
__device__ __forceinline__ float bfhi(unsigned int u) { return __uint_as_float(u & 0xffff0000u); }

// ===================== scatter edges into fixed buckets =====================
__global__ __launch_bounds__(256) void k_bscatter(const int* __restrict__ ei,
                                                  int* __restrict__ bcur,
                                                  unsigned int* __restrict__ ebuf,
                                                  int E, int NB) {
    __shared__ int h[768];
    __shared__ int wb[768];
    for (int i = threadIdx.x; i < 768; i += 256) h[i] = 0;
    __syncthreads();
    int base = blockIdx.x * 8192;
    int rk[32];
    #pragma unroll
    for (int it = 0; it < 32; ++it) {
        int e = base + it * 256 + threadIdx.x;
        rk[it] = (e < E) ? atomicAdd(&h[ei[E + e] >> 8], 1) : 0;
    }
    __syncthreads();
    for (int i = threadIdx.x; i < NB; i += 256) {
        int c = h[i];
        wb[i] = c ? atomicAdd(&bcur[i], c) : 0;
    }
    __syncthreads();
    #pragma unroll
    for (int it = 0; it < 32; ++it) {
        int e = base + it * 256 + threadIdx.x;
        if (e < E) {
            unsigned s = (unsigned)ei[e], d = (unsigned)ei[E + e];
            int bk = (int)(d >> 8);
            int pos = wb[bk] + rk[it];
            if (pos < (bk + 1) * CAP)              // overflow guard (never hit)
                ebuf[pos] = s | ((d & 255u) << 24);
        }
    }
}

// ================== per-bucket finalize: count+scan+place ===================
__global__ __launch_bounds__(256) void k_bfinal(const unsigned int* __restrict__ ebuf,
                                                const int* __restrict__ bcur,
                                                int* __restrict__ csr,
                                                int* __restrict__ rs,
                                                int* __restrict__ re,
                                                float* __restrict__ dinv, int N) {
    __shared__ int cnt[256];
    __shared__ int scn[256];
    __shared__ int cur[256];
    const int t = threadIdx.x, b = blockIdx.x;
    const int beg = b * CAP;
    const int cntE = min(bcur[b] - beg, CAP);
    cnt[t] = 0;
    __syncthreads();
    for (int j = t; j < cntE; j += 256)
        atomicAdd(&cnt[ebuf[beg + j] >> 24], 1);
    __syncthreads();
    int v = cnt[t];
    scn[t] = v;
    __syncthreads();
    for (int off = 1; off < 256; off <<= 1) {
        int x = (t >= off) ? scn[t - off] : 0;
        __syncthreads();
        scn[t] += x;
        __syncthreads();
    }
    int excl = scn[t] - v;
    int node = b * 256 + t;
    if (node < N) {
        rs[node]   = beg + excl;
        re[node]   = beg + excl + v;
        dinv[node] = rsqrtf((float)(1 + v));   // +1 self-loop
    }
    cur[t] = beg + excl;
    __syncthreads();
    for (int j = t; j < cntE; j += 256) {
        unsigned e = ebuf[beg + j];
        int pos = atomicAdd(&cur[e >> 24], 1);
        csr[pos] = (int)(e & 0x00FFFFFFu);
    }
}

// ========= weight prep (+ folded init): 3 weights, bf16 B-frag order ========
__global__ __launch_bounds__(256) void k_prepW3(const float* __restrict__ W0,
                                                const float* __restrict__ W1,
                                                const float* __restrict__ W2,
                                                unsigned short* __restrict__ Wf,
                                                int* __restrict__ bcur,
                                                float* __restrict__ stats, int NB) {
    int t = blockIdx.x * 256 + threadIdx.x;   // 0..6143
    if (t < NB) bcur[t] = t * CAP;            // folded k_init
    if (t < 512) stats[t] = 0.f;              // zeroes stats0 + stats1
    int wid = t >> 11;                        // 0,1,2
    int f = t & 2047;
    const float* W = (wid == 0) ? W0 : (wid == 1) ? W1 : W2;
    int C = (wid == 2) ? 40 : 128;
    int lane = f & 63, frag = f >> 6;
    int kt = frag & 3, ct = frag >> 2;
    int r = lane & 15, q = lane >> 4;
    int col = ct * 16 + r;
    int kbase = kt * 32 + q * 8;
    unsigned int v[8];
    #pragma unroll
    for (int j = 0; j < 8; ++j)
        v[j] = (col < C) ? f2bf(W[(size_t)(kbase + j) * C + col]) : 0u;
    uint4 o;
    o.x = v[0] | (v[1] << 16);
    o.y = v[2] | (v[3] << 16);
    o.z = v[4] | (v[5] << 16);
    o.w = v[6] | (v[7] << 16);
    ((uint4*)Wf)[t] = o;
}

// ============================== MFMA GEMM (layer 0) =========================
// No A-LDS: each wave loads its own 16x128 A-tile directly from global in
// MFMA fragment order. Used with stats=nullptr (no BN) for layer 0 only.
template <int NOCT, int OST>
__global__ __launch_bounds__(256) void k_gemm_mfma(
        const void* __restrict__ X, int xf32, const unsigned short* __restrict__ Wf,
        unsigned short* __restrict__ H, int N,
        const float* __restrict__ stats, const float* __restrict__ g,
        const float* __restrict__ be) {
    __shared__ unsigned short bF[NOCT * 4 * 512];
    __shared__ float2 bnss[128];
    const int tid = threadIdx.x;
    const int rowbase = blockIdx.x * 64;

    if (stats && tid < 128) {
        const float invN = 1.0f / (float)N;
        float mean = stats[tid] * invN;
        float var  = fmaf(-mean, mean, stats[128 + tid] * invN);
        float sc   = g[tid] * rsqrtf(var + BN_EPS);
        bnss[tid]  = make_float2(sc, fmaf(-mean, sc, be[tid]));
    }
    {   // stage B: NOCT col-tiles, lane-contiguous copy
        const uint4* src = (const uint4*)Wf;
        uint4* dst = (uint4*)bF;
        #pragma unroll
        for (int i = 0; i < NOCT; ++i) dst[tid + 256 * i] = src[tid + 256 * i];
    }
    __syncthreads();   // bF + bnss ready

    const int wave = tid >> 6, lane = tid & 63;
    const int r = lane & 15, q = lane >> 4;
    const int row  = rowbase + wave * 16 + r;
    const int rowc = min(row, N - 1);          // clamp: OOB rows computed, not stored

    bf16x8 afr[4];
    #pragma unroll
    for (int kt = 0; kt < 4; ++kt) {
        const int kc = kt * 32 + q * 8;
        float vv[8];
        if (xf32) {
            const float4* xp = (const float4*)((const float*)X + (size_t)rowc * 128 + kc);
            float4 p0 = xp[0], p1 = xp[1];
            vv[0] = p0.x; vv[1] = p0.y; vv[2] = p0.z; vv[3] = p0.w;
            vv[4] = p1.x; vv[5] = p1.y; vv[6] = p1.z; vv[7] = p1.w;
        } else {
            uint4 p = *((const uint4*)((const unsigned short*)X + (size_t)rowc * 128 + kc));
            vv[0] = bflo(p.x); vv[1] = bfhi(p.x);
            vv[2] = bflo(p.y); vv[3] = bfhi(p.y);
            vv[4] = bflo(p.z); vv[5] = bfhi(p.z);
            vv[6] = bflo(p.w); vv[7] = bfhi(p.w);
        }
        if (stats) {
            #pragma unroll
            for (int j = 0; j < 8; ++j) {
                float2 ss = bnss[kc + j];
                vv[j] = fmaxf(fmaf(vv[j], ss.x, ss.y), 0.0f);
            }
        }
        union { unsigned int u[4]; bf16x8 v; } pk;
        pk.u[0] = f2bf2(vv[0], vv[1]);
        pk.u[1] = f2bf2(vv[2], vv[3]);
        pk.u[2] = f2bf2(vv[4], vv[5]);
        pk.u[3] = f2bf2(vv[6], vv[7]);
        afr[kt] = pk.v;
    }

    f32x4 acc[NOCT];
    #pragma unroll
    for (int ct = 0; ct < NOCT; ++ct) acc[ct] = (f32x4){0.f, 0.f, 0.f, 0.f};

    #pragma unroll
    for (int kt = 0; kt < 4; ++kt) {
        #pragma unroll
        for (int ct = 0; ct < NOCT; ++ct) {
            bf16x8 b = ((const bf16x8*)bF)[(ct * 4 + kt) * 64 + lane];
            acc[ct] = __builtin_amdgcn_mfma_f32_16x16x32_bf16(afr[kt], b, acc[ct], 0, 0, 0);
        }
    }

    // C/D: col = ct*16 + r, row = q*4 + i; pack row-pairs, split halves
    #pragma unroll
    for (int ct = 0; ct < NOCT; ++ct) {
        #pragma unroll
        for (int i = 0; i < 4; i += 2) {
            int row0 = rowbase + wave * 16 + q * 4 + i;
            unsigned int pk = f2bf2(acc[ct][i], acc[ct][i + 1]);
            if (row0 < N)
                H[(size_t)row0 * OST + ct * 16 + r] = (unsigned short)pk;
            if (row0 + 1 < N)
                H[(size_t)(row0 + 1) * OST + ct * 16 + r] = (unsigned short)(pk >> 16);
        }
    }
}

// ========================= gather-based aggregate ===========================
// 16 lanes/node, uint4 (8ch) per lane. (proven form; layer 0 only)
__global__ __launch_bounds__(256) void k_agg128(
        const unsigned short* __restrict__ H, const int* __restrict__ rs,
        const int* __restrict__ re, const int* __restrict__ csr,
        const float* __restrict__ dinv, const float* __restrict__ b,
        unsigned short* __restrict__ outb, int N) {
    int lane = threadIdx.x & 15;
    int node = blockIdx.x * 16 + (threadIdx.x >> 4);
    if (node >= N) return;
    float dd  = dinv[node];
    int   beg = rs[node];
    int   end = re[node];
    uint4 hp  = ((const uint4*)(H + (size_t)node * 128))[lane];
    float4 bb0 = ((const float4*)b)[lane * 2];
    float4 bb1 = ((const float4*)b)[lane * 2 + 1];
    float sl = dd * dd;
    float a0 = fmaf(bflo(hp.x), sl, bb0.x), a1 = fmaf(bfhi(hp.x), sl, bb0.y);
    float a2 = fmaf(bflo(hp.y), sl, bb0.z), a3 = fmaf(bfhi(hp.y), sl, bb0.w);
    float a4 = fmaf(bflo(hp.z), sl, bb1.x), a5 = fmaf(bfhi(hp.z), sl, bb1.y);
    float a6 = fmaf(bflo(hp.w), sl, bb1.z), a7 = fmaf(bfhi(hp.w), sl, bb1.w);
    int j = beg;
    for (; j + 2 <= end; j += 2) {
        int s0 = csr[j], s1 = csr[j + 1];
        float n0 = dinv[s0] * dd, n1 = dinv[s1] * dd;
        uint4 v0 = ((const uint4*)(H + (size_t)s0 * 128))[lane];
        uint4 v1 = ((const uint4*)(H + (size_t)s1 * 128))[lane];
        a0 = fmaf(bflo(v0.x), n0, fmaf(bflo(v1.x), n1, a0));
        a1 = fmaf(bfhi(v0.x), n0, fmaf(bfhi(v1.x), n1, a1));
        a2 = fmaf(bflo(v0.y), n0, fmaf(bflo(v1.y), n1, a2));
        a3 = fmaf(bfhi(v0.y), n0, fmaf(bfhi(v1.y), n1, a3));
        a4 = fmaf(bflo(v0.z), n0, fmaf(bflo(v1.z), n1, a4));
        a5 = fmaf(bfhi(v0.z), n0, fmaf(bfhi(v1.z), n1, a5));
        a6 = fmaf(bflo(v0.w), n0, fmaf(bflo(v1.w), n1, a6));
        a7 = fmaf(bfhi(v0.w), n0, fmaf(bfhi(v1.w), n1, a7));
    }
    if (j < end) {
        int s0 = csr[j];
        float n0 = dinv[s0] * dd;
        uint4 v0 = ((const uint4*)(H + (size_t)s0 * 128))[lane];
        a0 = fmaf(bflo(v0.x), n0, a0); a1 = fmaf(bfhi(v0.x), n0, a1);
        a2 = fmaf(bflo(v0.y), n0, a2); a3 = fmaf(bfhi(v0.y), n0, a3);
        a4 = fmaf(bflo(v0.z), n0, a4); a5 = fmaf(bfhi(v0.z), n0, a5);
        a6 = fmaf(bflo(v0.w), n0, a6); a7 = fmaf(bfhi(v0.w), n0, a7);
    }
    uint4 o;
    o.x = f2bf2(a0, a1);
    o.y = f2bf2(a2, a3);
    o.z = f2bf2(a4, a5);
    o.w = f2bf2(a6, a7);
    ((uint4*)(outb + (size_t)node * 128))[lane] = o;
}

// ================= fused aggregate -> GEMM (layers 1 & 2) ===================
// agg(bn_relu(C)@W) == agg(bn_relu(C))@W  (segment-sum commutes with matmul).
// Gather 256B C rows (proven agg128 pattern), BN+ReLU in f32 in the loop
// (coeffs in 16 regs/lane: channels fixed per lane16), accumulate weighted
// sum incl. self-loop. Then: block's 16 nodes = one MFMA A-tile; stage via
// 4.3KB LDS; W-frags read direct from L2-hot Wf (NO B-LDS -> occupancy kept).
#define BNACC8(v, n)                                                   \
    a0 = fmaf(fmaxf(fmaf(bflo(v.x), sc0, sh0), 0.f), n, a0);           \
    a1 = fmaf(fmaxf(fmaf(bfhi(v.x), sc1, sh1), 0.f), n, a1);           \
    a2 = fmaf(fmaxf(fmaf(bflo(v.y), sc2, sh2), 0.f), n, a2);           \
    a3 = fmaf(fmaxf(fmaf(bfhi(v.y), sc3, sh3), 0.f), n, a3);           \
    a4 = fmaf(fmaxf(fmaf(bflo(v.z), sc4, sh4), 0.f), n, a4);           \
    a5 = fmaf(fmaxf(fmaf(bfhi(v.z), sc5, sh5), 0.f), n, a5);           \
    a6 = fmaf(fmaxf(fmaf(bflo(v.w), sc6, sh6), 0.f), n, a6);           \
    a7 = fmaf(fmaxf(fmaf(bfhi(v.w), sc7, sh7), 0.f), n, a7);

template <int NOCT, bool F32OUT>
__global__ __launch_bounds__(256) void k_fused_ag(
        const unsigned short* __restrict__ Hin, const int* __restrict__ rs,
        const int* __restrict__ re, const int* __restrict__ csr,
        const float* __restrict__ dinv,
        const float* __restrict__ stats, const float* __restrict__ g,
        const float* __restrict__ be,
        const unsigned short* __restrict__ Wfrag, const float* __restrict__ bias,
        void* __restrict__ outp, int N) {
    __shared__ unsigned short A[16][136];     // +8 pad: bank rotation
    const int t = threadIdx.x;
    const int lane16 = t & 15, grp = t >> 4;
    const int node = blockIdx.x * 16 + grp;
    const int cbase = lane16 * 8;
    const float invN = 1.0f / (float)N;

    // BN coefficients for this lane's 8 fixed channels -> registers
    float sc0, sc1, sc2, sc3, sc4, sc5, sc6, sc7;
    float sh0, sh1, sh2, sh3, sh4, sh5, sh6, sh7;
    {
        float scv[8], shv[8];
        #pragma unroll
        for (int k = 0; k < 8; ++k) {
            float mean = stats[cbase + k] * invN;
            float var  = fmaf(-mean, mean, stats[128 + cbase + k] * invN);
            float s    = g[cbase + k] * rsqrtf(var + BN_EPS);
            scv[k] = s; shv[k] = fmaf(-mean, s, be[cbase + k]);
        }
        sc0 = scv[0]; sc1 = scv[1]; sc2 = scv[2]; sc3 = scv[3];
        sc4 = scv[4]; sc5 = scv[5]; sc6 = scv[6]; sc7 = scv[7];
        sh0 = shv[0]; sh1 = shv[1]; sh2 = shv[2]; sh3 = shv[3];
        sh4 = shv[4]; sh5 = shv[5]; sh6 = shv[6]; sh7 = shv[7];
    }

    const bool valid = node < N;
    const int  nodec = valid ? node : 0;
    float dd  = valid ? dinv[nodec] : 0.f;
    int   beg = valid ? rs[nodec] : 0;
    int   end = valid ? re[nodec] : 0;
    uint4 hp  = ((const uint4*)(Hin + (size_t)nodec * 128))[lane16];
    float sl  = dd * dd;
    float a0 = 0.f, a1 = 0.f, a2 = 0.f, a3 = 0.f;
    float a4 = 0.f, a5 = 0.f, a6 = 0.f, a7 = 0.f;
    BNACC8(hp, sl);                           // self-loop (dd=0 if invalid)
    int j = beg;
    for (; j + 2 <= end; j += 2) {
        int s0 = csr[j], s1 = csr[j + 1];
        float n0 = dinv[s0] * dd, n1 = dinv[s1] * dd;
        uint4 v0 = ((const uint4*)(Hin + (size_t)s0 * 128))[lane16];
        uint4 v1 = ((const uint4*)(Hin + (size_t)s1 * 128))[lane16];
        BNACC8(v0, n0);
        BNACC8(v1, n1);
    }
    if (j < end) {
        int s0 = csr[j];
        float n0 = dinv[s0] * dd;
        uint4 v0 = ((const uint4*)(Hin + (size_t)s0 * 128))[lane16];
        BNACC8(v0, n0);
    }

    // stage aggregated bf16 A-tile (16 nodes x 128 ch)
    uint4 o;
    o.x = f2bf2(a0, a1);
    o.y = f2bf2(a2, a3);
    o.z = f2bf2(a4, a5);
    o.w = f2bf2(a6, a7);
    *((uint4*)&A[grp][lane16 * 8]) = o;
    __syncthreads();

    // MFMA: A from LDS, B direct from L2-hot Wf, bias post-MFMA
    const int wave = t >> 6, lane = t & 63;
    const int col = lane & 15, q = lane >> 4;
    bf16x8 afr[4];
    #pragma unroll
    for (int kt = 0; kt < 4; ++kt)
        afr[kt] = *((const bf16x8*)&A[col][kt * 32 + q * 8]);

    constexpr int CPW = (NOCT + 3) / 4;
    #pragma unroll
    for (int c = 0; c < CPW; ++c) {
        const int ct = wave + 4 * c;
        if (ct < NOCT) {
            f32x4 acc = (f32x4){0.f, 0.f, 0.f, 0.f};
            #pragma unroll
            for (int kt = 0; kt < 4; ++kt) {
                bf16x8 b = ((const bf16x8*)Wfrag)[(ct * 4 + kt) * 64 + lane];
                acc = __builtin_amdgcn_mfma_f32_16x16x32_bf16(afr[kt], b, acc, 0, 0, 0);
            }
            if (F32OUT) {
                const int ch = ct * 16 + col;
                if (ch < 40) {
                    float bv = bias[ch];
                    float* out = (float*)outp;
                    #pragma unroll
                    for (int i = 0; i < 4; ++i) {
                        int r0 = blockIdx.x * 16 + q * 4 + i;
                        if (r0 < N) out[(size_t)r0 * 40 + ch] = acc[i] + bv;
                    }
                }
            } else {
                float bv = bias[ct * 16 + col];
                unsigned short* H2 = (unsigned short*)outp;
                #pragma unroll
                for (int i = 0; i < 4; i += 2) {
                    int r0 = blockIdx.x * 16 + q * 4 + i;
                    unsigned int pk = f2bf2(acc[i] + bv, acc[i + 1] + bv);
                    if (r0 < N)
                        H2[(size_t)r0 * 128 + ct * 16 + col] = (unsigned short)pk;
                    if (r0 + 1 < N)
                        H2[(size_t)(r0 + 1) * 128 + ct * 16 + col] = (unsigned short)(pk >> 16);
                }
            }
        }
    }
}

// =============================== BN stats ===================================
__global__ __launch_bounds__(256) void k_bnstats(
        const unsigned short* __restrict__ Bb, float* __restrict__ stats, int N) {
    __shared__ float red[2][16][128];
    const int t = threadIdx.x;
    const int lane16 = t & 15, grp = t >> 4;
    const int cbase = lane16 * 8;
    float s[8], q[8];
    #pragma unroll
    for (int k = 0; k < 8; ++k) { s[k] = 0.f; q[k] = 0.f; }

    const int step = gridDim.x * 16;
    for (int r = blockIdx.x * 16 + grp; r < N; r += 2 * step) {
        uint4 p0 = *((const uint4*)(Bb + (size_t)r * 128 + cbase));
        int r1 = r + step;
        if (r1 < N) {
            uint4 p1 = *((const uint4*)(Bb + (size_t)r1 * 128 + cbase));
            float v[8] = {bflo(p1.x), bfhi(p1.x), bflo(p1.y), bfhi(p1.y),
                          bflo(p1.z), bfhi(p1.z), bflo(p1.w), bfhi(p1.w)};
            #pragma unroll
            for (int k = 0; k < 8; ++k) { s[k] += v[k]; q[k] = fmaf(v[k], v[k], q[k]); }
        }
        float u[8] = {bflo(p0.x), bfhi(p0.x), bflo(p0.y), bfhi(p0.y),
                      bflo(p0.z), bfhi(p0.z), bflo(p0.w), bfhi(p0.w)};
        #pragma unroll
        for (int k = 0; k < 8; ++k) { s[k] += u[k]; q[k] = fmaf(u[k], u[k], q[k]); }
    }
    #pragma unroll
    for (int k = 0; k < 8; ++k) {
        red[0][grp][cbase + k] = s[k];
        red[1][grp][cbase + k] = q[k];
    }
    __syncthreads();
    if (t < 128) {
        float acc = 0.f;
        #pragma unroll
        for (int g = 0; g < 16; ++g) acc += red[0][g][t];
        unsafeAtomicAdd(&stats[t], acc);
    } else {
        int c = t - 128;
        float acc = 0.f;
        #pragma unroll
        for (int g = 0; g < 16; ++g) acc += red[1][g][c];
        unsafeAtomicAdd(&stats[128 + c], acc);
    }
}

// ================================ launch ====================================
extern "C" void kernel_launch(void* const* d_in, const int* in_sizes, int n_in,
                              void* d_out, int out_size, void* d_ws, size_t ws_size,
                              hipStream_t stream) {
    const float* x   = (const float*)d_in[0];
    const int*   ei  = (const int*)d_in[1];      // int64 in ref -> int32 from harness
    const float* W0  = (const float*)d_in[2];
    const float* b0  = (const float*)d_in[3];
    const float* g0  = (const float*)d_in[4];
    const float* be0 = (const float*)d_in[5];
    const float* W1  = (const float*)d_in[6];
    const float* b1  = (const float*)d_in[7];
    const float* g1  = (const float*)d_in[8];
    const float* be1 = (const float*)d_in[9];
    const float* W2  = (const float*)d_in[10];
    const float* b2  = (const float*)d_in[11];
    float* out = (float*)d_out;

    const int N  = in_sizes[0] / 128;   // 170000
    const int E  = in_sizes[1] / 2;     // 1200000
    const int NB = (N + 255) >> 8;      // 665 buckets
    const int EB = (E + 8191) / 8192;   // 147 edge-chunk blocks

    // ws layout (4B units)
    float* ws   = (float*)d_ws;
    size_t Npad = ((size_t)N + 511) & ~(size_t)511;
    size_t BCAP = (size_t)NB * CAP;
    float* dinv = ws;
    int*   rs   = (int*)(ws + Npad);
    int*   re   = rs + Npad;
    int*   csr  = re + Npad;                            // BCAP
    unsigned int* ebuf = (unsigned int*)(csr + BCAP);   // BCAP
    int*   bcur = (int*)(ebuf + BCAP);                  // 1024
    float* stats0 = (float*)(bcur + 1024);              // 256
    float* stats1 = stats0 + 256;                       // 256
    unsigned short* Wf = (unsigned short*)(stats1 + 256); // 3*16384 ushort
    unsigned short* Hb = Wf + 3 * 16384;                // Npad*128 bf16
    unsigned short* Bb = Hb + Npad * 128;               // Npad*128 bf16

    // ---- prep (init folded) + CSR build: 3 dispatches ----
    k_prepW3  <<<24, 256, 0, stream>>>(W0, W1, W2, Wf, bcur, stats0, NB);
    k_bscatter<<<EB, 256, 0, stream>>>(ei, bcur, ebuf, E, NB);
    k_bfinal  <<<NB, 256, 0, stream>>>(ebuf, bcur, csr, rs, re, dinv, N);

    int gemm_grid = (N + 63) / 64;
    int agg_grid  = (N + 15) / 16;

    // ---- layer 0: GEMM then aggregate (x is f32: gather-first too costly) ----
    k_gemm_mfma<8, 128><<<gemm_grid, 256, 0, stream>>>(x, 1, Wf, Hb, N,
                                                       nullptr, nullptr, nullptr);
    k_agg128<<<agg_grid, 256, 0, stream>>>(Hb, rs, re, csr, dinv, b0, Bb, N);
    k_bnstats<<<512, 256, 0, stream>>>(Bb, stats0, N);

    // ---- layer 1 fused: c2 = agg(bn_relu(c1)) @ W1 + b1  (Bb -> Hb) ----
    k_fused_ag<8, false><<<agg_grid, 256, 0, stream>>>(Bb, rs, re, csr, dinv,
                                                       stats0, g0, be0,
                                                       Wf + 16384, b1, Hb, N);
    k_bnstats<<<512, 256, 0, stream>>>(Hb, stats1, N);

    // ---- layer 2 fused: out = agg(bn_relu(c2)) @ W2 + b2  (Hb -> out) ----
    k_fused_ag<3, true><<<agg_grid, 256, 0, stream>>>(Hb, rs, re, csr, dinv,
                                                      stats1, g1, be1,
                                                      Wf + 2 * 16384, b2, out, N);
}

// Round 7
// 447.501 us; speedup vs baseline: 1.0249x; 1.0249x over previous
//
#include <hip/hip_runtime.h>

#define BN_EPS 1e-5f
#define CAP 3072   // per-bucket edge capacity (mean 1805, +30 sigma; guarded)

using bf16x8 = __attribute__((ext_vector_type(8))) short;
using f32x4  = __attribute__((ext_vector_type(4))) float;

__device__ __forceinline__ unsigned int f2bf(float f) {   // RTNE fp32->bf16
    unsigned int u = __float_as_uint(f);
    u += 0x7fffu + ((u >> 16) & 1u);
    return u >> 16;
}
// packed RTNE fp32x2 -> bf16x2 (bit-identical to f2bf pair)
__device__ __forceinline__ unsigned int f2bf2(float lo, float hi) {
    unsigned int r;
    asm("v_cvt_pk_bf16_f32 %0, %1, %2" : "=v"(r) : "v"(lo), "v"(hi));
    return r;
}
__device__ __forceinline__ float bflo(unsigned int u) { return __uint_as_float(u << 16); }
__device__ __forceinline__ float bfhi(unsigned int u) { return __uint_as_float(u & 0xffff0000u); }

// ========= dispatch 1: weight prep (+ bcur/stats init, own dispatch) ========
// MUST complete before k_bscatter (bcur init -> atomicAdd ordering).
__global__ __launch_bounds__(256) void k_prepW3(const float* __restrict__ W0,
                                                const float* __restrict__ W1,
                                                const float* __restrict__ W2,
                                                unsigned short* __restrict__ Wf,
                                                int* __restrict__ bcur,
                                                float* __restrict__ stats, int NB) {
    int t = blockIdx.x * 256 + threadIdx.x;   // 0..6143
    if (t < NB) bcur[t] = t * CAP;            // folded k_init
    if (t < 512) stats[t] = 0.f;              // zeroes stats0 + stats1
    int wid = t >> 11;                        // 0,1,2
    int f = t & 2047;
    const float* W = (wid == 0) ? W0 : (wid == 1) ? W1 : W2;
    int C = (wid == 2) ? 40 : 128;
    int lane = f & 63, frag = f >> 6;
    int kt = frag & 3, ct = frag >> 2;
    int r = lane & 15, q = lane >> 4;
    int col = ct * 16 + r;
    int kbase = kt * 32 + q * 8;
    unsigned int v[8];
    #pragma unroll
    for (int j = 0; j < 8; ++j)
        v[j] = (col < C) ? f2bf(W[(size_t)(kbase + j) * C + col]) : 0u;
    uint4 o;
    o.x = v[0] | (v[1] << 16);
    o.y = v[2] | (v[3] << 16);
    o.z = v[4] | (v[5] << 16);
    o.w = v[6] | (v[7] << 16);
    ((uint4*)Wf)[t] = o;
}

// ===================== scatter edges into fixed buckets =====================
__global__ __launch_bounds__(256) void k_bscatter(const int* __restrict__ ei,
                                                  int* __restrict__ bcur,
                                                  unsigned int* __restrict__ ebuf,
                                                  int E, int NB) {
    __shared__ int h[768];
    __shared__ int wb[768];
    for (int i = threadIdx.x; i < 768; i += 256) h[i] = 0;
    __syncthreads();
    int base = blockIdx.x * 8192;
    int rk[32];
    #pragma unroll
    for (int it = 0; it < 32; ++it) {
        int e = base + it * 256 + threadIdx.x;
        rk[it] = (e < E) ? atomicAdd(&h[ei[E + e] >> 8], 1) : 0;
    }
    __syncthreads();
    for (int i = threadIdx.x; i < NB; i += 256) {
        int c = h[i];
        wb[i] = c ? atomicAdd(&bcur[i], c) : 0;
    }
    __syncthreads();
    #pragma unroll
    for (int it = 0; it < 32; ++it) {
        int e = base + it * 256 + threadIdx.x;
        if (e < E) {
            unsigned s = (unsigned)ei[e], d = (unsigned)ei[E + e];
            int bk = (int)(d >> 8);
            int pos = wb[bk] + rk[it];
            if (pos >= bk * CAP && pos < (bk + 1) * CAP)   // two-sided guard
                ebuf[pos] = s | ((d & 255u) << 24);
        }
    }
}

// ============ dispatch 3: CSR finalize || layer-0 GEMM (independent) ========
// blocks [0,NB): bfinal role (consumes ebuf/bcur from dispatch 2).
// blocks [NB, NB+gemm_grid): gemm0 role (consumes Wf from dispatch 1 + x).
// No intra-dispatch producer-consumer: race-free.
__global__ __launch_bounds__(256) void k_final_gemm0(
        const unsigned int* __restrict__ ebuf, const int* __restrict__ bcur,
        int* __restrict__ csr, int* __restrict__ rs, int* __restrict__ re,
        float* __restrict__ dinv,
        const float* __restrict__ X, const unsigned short* __restrict__ Wf,
        unsigned short* __restrict__ H, int N, int NB) {
    __shared__ int cnt[256];
    __shared__ int scn[256];
    __shared__ int cur[256];
    __shared__ unsigned short bF[8 * 4 * 512];
    const int t = threadIdx.x;
    if (blockIdx.x < (unsigned)NB) {
        // ---- bfinal role ----
        const int b = blockIdx.x;
        const int beg = b * CAP;
        const int cntE = min(bcur[b] - beg, CAP);
        cnt[t] = 0;
        __syncthreads();
        for (int j = t; j < cntE; j += 256)
            atomicAdd(&cnt[ebuf[beg + j] >> 24], 1);
        __syncthreads();
        int v = cnt[t];
        scn[t] = v;
        __syncthreads();
        for (int off = 1; off < 256; off <<= 1) {
            int x = (t >= off) ? scn[t - off] : 0;
            __syncthreads();
            scn[t] += x;
            __syncthreads();
        }
        int excl = scn[t] - v;
        int node = b * 256 + t;
        if (node < N) {
            rs[node]   = beg + excl;
            re[node]   = beg + excl + v;
            dinv[node] = rsqrtf((float)(1 + v));   // +1 self-loop
        }
        cur[t] = beg + excl;
        __syncthreads();
        for (int j = t; j < cntE; j += 256) {
            unsigned e = ebuf[beg + j];
            int pos = atomicAdd(&cur[e >> 24], 1);
            csr[pos] = (int)(e & 0x00FFFFFFu);
        }
        return;
    }
    // ---- gemm0 role: H[N,128] = bf16(X[N,128]_f32 @ W0) ----
    const int rowbase = (blockIdx.x - NB) * 64;
    {   // stage B: 8 col-tiles
        const uint4* src = (const uint4*)Wf;
        uint4* dst = (uint4*)bF;
        #pragma unroll
        for (int i = 0; i < 8; ++i) dst[t + 256 * i] = src[t + 256 * i];
    }
    __syncthreads();

    const int wave = t >> 6, lane = t & 63;
    const int r = lane & 15, q = lane >> 4;
    const int row  = rowbase + wave * 16 + r;
    const int rowc = min(row, N - 1);          // clamp: OOB rows computed, not stored

    bf16x8 afr[4];
    #pragma unroll
    for (int kt = 0; kt < 4; ++kt) {
        const int kc = kt * 32 + q * 8;
        const float4* xp = (const float4*)(X + (size_t)rowc * 128 + kc);
        float4 p0 = xp[0], p1 = xp[1];
        union { unsigned int u[4]; bf16x8 v; } pk;
        pk.u[0] = f2bf2(p0.x, p0.y);
        pk.u[1] = f2bf2(p0.z, p0.w);
        pk.u[2] = f2bf2(p1.x, p1.y);
        pk.u[3] = f2bf2(p1.z, p1.w);
        afr[kt] = pk.v;
    }

    f32x4 acc[8];
    #pragma unroll
    for (int ct = 0; ct < 8; ++ct) acc[ct] = (f32x4){0.f, 0.f, 0.f, 0.f};
    #pragma unroll
    for (int kt = 0; kt < 4; ++kt) {
        #pragma unroll
        for (int ct = 0; ct < 8; ++ct) {
            bf16x8 b = ((const bf16x8*)bF)[(ct * 4 + kt) * 64 + lane];
            acc[ct] = __builtin_amdgcn_mfma_f32_16x16x32_bf16(afr[kt], b, acc[ct], 0, 0, 0);
        }
    }
    #pragma unroll
    for (int ct = 0; ct < 8; ++ct) {
        #pragma unroll
        for (int i = 0; i < 4; i += 2) {
            int row0 = rowbase + wave * 16 + q * 4 + i;
            unsigned int pk = f2bf2(acc[ct][i], acc[ct][i + 1]);
            if (row0 < N)
                H[(size_t)row0 * 128 + ct * 16 + r] = (unsigned short)pk;
            if (row0 + 1 < N)
                H[(size_t)(row0 + 1) * 128 + ct * 16 + r] = (unsigned short)(pk >> 16);
        }
    }
}

// ============================== MFMA GEMM (layers 1,2) ======================
// No A-LDS: each wave loads its own 16x128 A-tile directly from global in
// MFMA fragment order. BN scale/shift precomputed once per block into LDS.
template <int NOCT, int OST>
__global__ __launch_bounds__(256) void k_gemm_mfma(
        const unsigned short* __restrict__ X, const unsigned short* __restrict__ Wf,
        unsigned short* __restrict__ H, int N,
        const float* __restrict__ stats, const float* __restrict__ g,
        const float* __restrict__ be) {
    __shared__ unsigned short bF[NOCT * 4 * 512];
    __shared__ float2 bnss[128];
    const int tid = threadIdx.x;
    const int rowbase = blockIdx.x * 64;

    if (tid < 128) {
        const float invN = 1.0f / (float)N;
        float mean = stats[tid] * invN;
        float var  = fmaf(-mean, mean, stats[128 + tid] * invN);
        float sc   = g[tid] * rsqrtf(var + BN_EPS);
        bnss[tid]  = make_float2(sc, fmaf(-mean, sc, be[tid]));
    }
    {   // stage B: NOCT col-tiles, lane-contiguous copy
        const uint4* src = (const uint4*)Wf;
        uint4* dst = (uint4*)bF;
        #pragma unroll
        for (int i = 0; i < NOCT; ++i) dst[tid + 256 * i] = src[tid + 256 * i];
    }
    __syncthreads();   // bF + bnss ready

    const int wave = tid >> 6, lane = tid & 63;
    const int r = lane & 15, q = lane >> 4;
    const int row  = rowbase + wave * 16 + r;
    const int rowc = min(row, N - 1);          // clamp: OOB rows computed, not stored

    bf16x8 afr[4];
    #pragma unroll
    for (int kt = 0; kt < 4; ++kt) {
        const int kc = kt * 32 + q * 8;
        uint4 p = *((const uint4*)(X + (size_t)rowc * 128 + kc));
        float vv[8];
        vv[0] = bflo(p.x); vv[1] = bfhi(p.x);
        vv[2] = bflo(p.y); vv[3] = bfhi(p.y);
        vv[4] = bflo(p.z); vv[5] = bfhi(p.z);
        vv[6] = bflo(p.w); vv[7] = bfhi(p.w);
        #pragma unroll
        for (int j = 0; j < 8; ++j) {
            float2 ss = bnss[kc + j];
            vv[j] = fmaxf(fmaf(vv[j], ss.x, ss.y), 0.0f);
        }
        union { unsigned int u[4]; bf16x8 v; } pk;
        pk.u[0] = f2bf2(vv[0], vv[1]);
        pk.u[1] = f2bf2(vv[2], vv[3]);
        pk.u[2] = f2bf2(vv[4], vv[5]);
        pk.u[3] = f2bf2(vv[6], vv[7]);
        afr[kt] = pk.v;
    }

    f32x4 acc[NOCT];
    #pragma unroll
    for (int ct = 0; ct < NOCT; ++ct) acc[ct] = (f32x4){0.f, 0.f, 0.f, 0.f};

    #pragma unroll
    for (int kt = 0; kt < 4; ++kt) {
        #pragma unroll
        for (int ct = 0; ct < NOCT; ++ct) {
            bf16x8 b = ((const bf16x8*)bF)[(ct * 4 + kt) * 64 + lane];
            acc[ct] = __builtin_amdgcn_mfma_f32_16x16x32_bf16(afr[kt], b, acc[ct], 0, 0, 0);
        }
    }

    // C/D: col = ct*16 + r, row = q*4 + i; pack row-pairs, split halves
    #pragma unroll
    for (int ct = 0; ct < NOCT; ++ct) {
        #pragma unroll
        for (int i = 0; i < 4; i += 2) {
            int row0 = rowbase + wave * 16 + q * 4 + i;
            unsigned int pk = f2bf2(acc[ct][i], acc[ct][i + 1]);
            if (row0 < N)
                H[(size_t)row0 * OST + ct * 16 + r] = (unsigned short)pk;
            if (row0 + 1 < N)
                H[(size_t)(row0 + 1) * OST + ct * 16 + r] = (unsigned short)(pk >> 16);
        }
    }
}

// ========================= gather-based aggregate ===========================
// 16 lanes/node, uint4 (8ch) per lane. (proven roofline form: ~6.6 TB/s logical)
__global__ __launch_bounds__(256) void k_agg128(
        const unsigned short* __restrict__ H, const int* __restrict__ rs,
        const int* __restrict__ re, const int* __restrict__ csr,
        const float* __restrict__ dinv, const float* __restrict__ b,
        unsigned short* __restrict__ outb, int N) {
    int lane = threadIdx.x & 15;
    int node = blockIdx.x * 16 + (threadIdx.x >> 4);
    if (node >= N) return;
    float dd  = dinv[node];
    int   beg = rs[node];
    int   end = re[node];
    uint4 hp  = ((const uint4*)(H + (size_t)node * 128))[lane];
    float4 bb0 = ((const float4*)b)[lane * 2];
    float4 bb1 = ((const float4*)b)[lane * 2 + 1];
    float sl = dd * dd;
    float a0 = fmaf(bflo(hp.x), sl, bb0.x), a1 = fmaf(bfhi(hp.x), sl, bb0.y);
    float a2 = fmaf(bflo(hp.y), sl, bb0.z), a3 = fmaf(bfhi(hp.y), sl, bb0.w);
    float a4 = fmaf(bflo(hp.z), sl, bb1.x), a5 = fmaf(bfhi(hp.z), sl, bb1.y);
    float a6 = fmaf(bflo(hp.w), sl, bb1.z), a7 = fmaf(bfhi(hp.w), sl, bb1.w);
    int j = beg;
    for (; j + 2 <= end; j += 2) {
        int s0 = csr[j], s1 = csr[j + 1];
        float n0 = dinv[s0] * dd, n1 = dinv[s1] * dd;
        uint4 v0 = ((const uint4*)(H + (size_t)s0 * 128))[lane];
        uint4 v1 = ((const uint4*)(H + (size_t)s1 * 128))[lane];
        a0 = fmaf(bflo(v0.x), n0, fmaf(bflo(v1.x), n1, a0));
        a1 = fmaf(bfhi(v0.x), n0, fmaf(bfhi(v1.x), n1, a1));
        a2 = fmaf(bflo(v0.y), n0, fmaf(bflo(v1.y), n1, a2));
        a3 = fmaf(bfhi(v0.y), n0, fmaf(bfhi(v1.y), n1, a3));
        a4 = fmaf(bflo(v0.z), n0, fmaf(bflo(v1.z), n1, a4));
        a5 = fmaf(bfhi(v0.z), n0, fmaf(bfhi(v1.z), n1, a5));
        a6 = fmaf(bflo(v0.w), n0, fmaf(bflo(v1.w), n1, a6));
        a7 = fmaf(bfhi(v0.w), n0, fmaf(bfhi(v1.w), n1, a7));
    }
    if (j < end) {
        int s0 = csr[j];
        float n0 = dinv[s0] * dd;
        uint4 v0 = ((const uint4*)(H + (size_t)s0 * 128))[lane];
        a0 = fmaf(bflo(v0.x), n0, a0); a1 = fmaf(bfhi(v0.x), n0, a1);
        a2 = fmaf(bflo(v0.y), n0, a2); a3 = fmaf(bfhi(v0.y), n0, a3);
        a4 = fmaf(bflo(v0.z), n0, a4); a5 = fmaf(bfhi(v0.z), n0, a5);
        a6 = fmaf(bflo(v0.w), n0, a6); a7 = fmaf(bfhi(v0.w), n0, a7);
    }
    uint4 o;
    o.x = f2bf2(a0, a1);
    o.y = f2bf2(a2, a3);
    o.z = f2bf2(a4, a5);
    o.w = f2bf2(a6, a7);
    ((uint4*)(outb + (size_t)node * 128))[lane] = o;
}

// 40-ch final from line-aligned stride-64 H (1 cache line per gathered row)
__global__ __launch_bounds__(256) void k_agg40(
        const unsigned short* __restrict__ H, const int* __restrict__ rs,
        const int* __restrict__ re, const int* __restrict__ csr,
        const float* __restrict__ dinv, const float* __restrict__ b,
        float* __restrict__ out, int N) {
    int lane = threadIdx.x & 15;
    int node = blockIdx.x * 16 + (threadIdx.x >> 4);
    if (node >= N || lane >= 10) return;
    float dd  = dinv[node];
    int   beg = rs[node];
    int   end = re[node];
    uint2 hp  = ((const uint2*)(H + (size_t)node * 64))[lane];
    float4 bb = ((const float4*)b)[lane];
    float  sl = dd * dd;
    float4 acc = make_float4(fmaf(bflo(hp.x), sl, bb.x), fmaf(bfhi(hp.x), sl, bb.y),
                             fmaf(bflo(hp.y), sl, bb.z), fmaf(bfhi(hp.y), sl, bb.w));
    int j = beg;
    for (; j + 2 <= end; j += 2) {
        int s0 = csr[j], s1 = csr[j + 1];
        float n0 = dinv[s0] * dd, n1 = dinv[s1] * dd;
        uint2 v0 = ((const uint2*)(H + (size_t)s0 * 64))[lane];
        uint2 v1 = ((const uint2*)(H + (size_t)s1 * 64))[lane];
        acc.x = fmaf(bflo(v0.x), n0, fmaf(bflo(v1.x), n1, acc.x));
        acc.y = fmaf(bfhi(v0.x), n0, fmaf(bfhi(v1.x), n1, acc.y));
        acc.z = fmaf(bflo(v0.y), n0, fmaf(bflo(v1.y), n1, acc.z));
        acc.w = fmaf(bfhi(v0.y), n0, fmaf(bfhi(v1.y), n1, acc.w));
    }
    if (j < end) {
        int s0 = csr[j];
        float n0 = dinv[s0] * dd;
        uint2 v0 = ((const uint2*)(H + (size_t)s0 * 64))[lane];
        acc.x = fmaf(bflo(v0.x), n0, acc.x);
        acc.y = fmaf(bfhi(v0.x), n0, acc.y);
        acc.z = fmaf(bflo(v0.y), n0, acc.z);
        acc.w = fmaf(bfhi(v0.y), n0, acc.w);
    }
    ((float4*)(out + (size_t)node * 40))[lane] = acc;
}

// =============================== BN stats ===================================
__global__ __launch_bounds__(256) void k_bnstats(
        const unsigned short* __restrict__ Bb, float* __restrict__ stats, int N) {
    __shared__ float red[2][16][128];
    const int t = threadIdx.x;
    const int lane16 = t & 15, grp = t >> 4;
    const int cbase = lane16 * 8;
    float s[8], q[8];
    #pragma unroll
    for (int k = 0; k < 8; ++k) { s[k] = 0.f; q[k] = 0.f; }

    const int step = gridDim.x * 16;
    for (int r = blockIdx.x * 16 + grp; r < N; r += 2 * step) {
        uint4 p0 = *((const uint4*)(Bb + (size_t)r * 128 + cbase));
        int r1 = r + step;
        if (r1 < N) {
            uint4 p1 = *((const uint4*)(Bb + (size_t)r1 * 128 + cbase));
            float v[8] = {bflo(p1.x), bfhi(p1.x), bflo(p1.y), bfhi(p1.y),
                          bflo(p1.z), bfhi(p1.z), bflo(p1.w), bfhi(p1.w)};
            #pragma unroll
            for (int k = 0; k < 8; ++k) { s[k] += v[k]; q[k] = fmaf(v[k], v[k], q[k]); }
        }
        float u[8] = {bflo(p0.x), bfhi(p0.x), bflo(p0.y), bfhi(p0.y),
                      bflo(p0.z), bfhi(p0.z), bflo(p0.w), bfhi(p0.w)};
        #pragma unroll
        for (int k = 0; k < 8; ++k) { s[k] += u[k]; q[k] = fmaf(u[k], u[k], q[k]); }
    }
    #pragma unroll
    for (int k = 0; k < 8; ++k) {
        red[0][grp][cbase + k] = s[k];
        red[1][grp][cbase + k] = q[k];
    }
    __syncthreads();
    if (t < 128) {
        float acc = 0.f;
        #pragma unroll
        for (int g = 0; g < 16; ++g) acc += red[0][g][t];
        unsafeAtomicAdd(&stats[t], acc);
    } else {
        int c = t - 128;
        float acc = 0.f;
        #pragma unroll
        for (int g = 0; g < 16; ++g) acc += red[1][g][c];
        unsafeAtomicAdd(&stats[128 + c], acc);
    }
}

// ================================ launch ====================================
extern "C" void kernel_launch(void* const* d_in, const int* in_sizes, int n_in,
                              void* d_out, int out_size, void* d_ws, size_t ws_size,
                              hipStream_t stream) {
    const float* x   = (const float*)d_in[0];
    const int*   ei  = (const int*)d_in[1];      // int64 in ref -> int32 from harness
    const float* W0  = (const float*)d_in[2];
    const float* b0  = (const float*)d_in[3];
    const float* g0  = (const float*)d_in[4];
    const float* be0 = (const float*)d_in[5];
    const float* W1  = (const float*)d_in[6];
    const float* b1  = (const float*)d_in[7];
    const float* g1  = (const float*)d_in[8];
    const float* be1 = (const float*)d_in[9];
    const float* W2  = (const float*)d_in[10];
    const float* b2  = (const float*)d_in[11];
    float* out = (float*)d_out;

    const int N  = in_sizes[0] / 128;   // 170000
    const int E  = in_sizes[1] / 2;     // 1200000
    const int NB = (N + 255) >> 8;      // 665 buckets
    const int EB = (E + 8191) / 8192;   // 147 edge-chunk blocks

    // ws layout (4B units)
    float* ws   = (float*)d_ws;
    size_t Npad = ((size_t)N + 511) & ~(size_t)511;
    size_t BCAP = (size_t)NB * CAP;
    float* dinv = ws;
    int*   rs   = (int*)(ws + Npad);
    int*   re   = rs + Npad;
    int*   csr  = re + Npad;                            // BCAP
    unsigned int* ebuf = (unsigned int*)(csr + BCAP);   // BCAP
    int*   bcur = (int*)(ebuf + BCAP);                  // 1024
    float* stats0 = (float*)(bcur + 1024);              // 256
    float* stats1 = stats0 + 256;                       // 256
    unsigned short* Wf = (unsigned short*)(stats1 + 256); // 3*16384 ushort
    unsigned short* Hb = Wf + 3 * 16384;                // Npad*128 bf16
    unsigned short* Bb = Hb + Npad * 128;               // Npad*128 bf16

    int gemm_grid = (N + 63) / 64;
    int agg_grid  = (N + 15) / 16;

    // ---- dispatch 1: Wf prep + bcur/stats init (must precede bscatter) ----
    k_prepW3  <<<24, 256, 0, stream>>>(W0, W1, W2, Wf, bcur, stats0, NB);
    // ---- dispatch 2: edge scatter ----
    k_bscatter<<<EB, 256, 0, stream>>>(ei, bcur, ebuf, E, NB);
    // ---- dispatch 3: CSR finalize || layer-0 GEMM (independent roles) ----
    k_final_gemm0<<<NB + gemm_grid, 256, 0, stream>>>(ebuf, bcur, csr, rs, re,
                                                      dinv, x, Wf, Hb, N, NB);

    // ---- layer 0 aggregate + stats ----
    k_agg128<<<agg_grid, 256, 0, stream>>>(Hb, rs, re, csr, dinv, b0, Bb, N);
    k_bnstats<<<512, 256, 0, stream>>>(Bb, stats0, N);

    // ---- layer 1 (BN0+ReLU fused into GEMM staging, LDS-precomputed) ----
    k_gemm_mfma<8, 128><<<gemm_grid, 256, 0, stream>>>(Bb, Wf + 16384, Hb, N,
                                                       stats0, g0, be0);
    k_agg128<<<agg_grid, 256, 0, stream>>>(Hb, rs, re, csr, dinv, b1, Bb, N);
    k_bnstats<<<512, 256, 0, stream>>>(Bb, stats1, N);

    // ---- layer 2 (BN1+ReLU fused) -> line-aligned 64-stride H -> 40-ch out ----
    k_gemm_mfma<3, 64><<<gemm_grid, 256, 0, stream>>>(Bb, Wf + 2 * 16384, Hb, N,
                                                      stats1, g1, be1);
    k_agg40<<<agg_grid, 256, 0, stream>>>(Hb, rs, re, csr, dinv, b2, out, N);
}

// Round 8
// 439.223 us; speedup vs baseline: 1.0442x; 1.0188x over previous
//
#include <hip/hip_runtime.h>

#define BN_EPS 1e-5f
#define CAP 3072   // per-bucket edge capacity (mean 1805, +30 sigma; guarded)

using bf16x8 = __attribute__((ext_vector_type(8))) short;
using f32x4  = __attribute__((ext_vector_type(4))) float;

__device__ __forceinline__ unsigned int f2bf(float f) {   // RTNE fp32->bf16
    unsigned int u = __float_as_uint(f);
    u += 0x7fffu + ((u >> 16) & 1u);
    return u >> 16;
}
// packed RTNE fp32x2 -> bf16x2 (bit-identical to f2bf pair)
__device__ __forceinline__ unsigned int f2bf2(float lo, float hi) {
    unsigned int r;
    asm("v_cvt_pk_bf16_f32 %0, %1, %2" : "=v"(r) : "v"(lo), "v"(hi));
    return r;
}
__device__ __forceinline__ float bflo(unsigned int u) { return __uint_as_float(u << 16); }
__device__ __forceinline__ float bfhi(unsigned int u) { return __uint_as_float(u & 0xffff0000u); }

// ========= dispatch 1: weight prep (+ bcur/stats init, own dispatch) ========
// MUST complete before k_bscatter (bcur init -> atomicAdd ordering).
// stats = 2 layers x 8 slabs x 256 floats = 4096 floats zeroed.
__global__ __launch_bounds__(256) void k_prepW3(const float* __restrict__ W0,
                                                const float* __restrict__ W1,
                                                const float* __restrict__ W2,
                                                unsigned short* __restrict__ Wf,
                                                int* __restrict__ bcur,
                                                float* __restrict__ stats, int NB) {
    int t = blockIdx.x * 256 + threadIdx.x;   // 0..6143
    if (t < NB) bcur[t] = t * CAP;            // folded k_init
    if (t < 4096) stats[t] = 0.f;             // zeroes stats0+stats1 slabs
    int wid = t >> 11;                        // 0,1,2
    int f = t & 2047;
    const float* W = (wid == 0) ? W0 : (wid == 1) ? W1 : W2;
    int C = (wid == 2) ? 40 : 128;
    int lane = f & 63, frag = f >> 6;
    int kt = frag & 3, ct = frag >> 2;
    int r = lane & 15, q = lane >> 4;
    int col = ct * 16 + r;
    int kbase = kt * 32 + q * 8;
    unsigned int v[8];
    #pragma unroll
    for (int j = 0; j < 8; ++j)
        v[j] = (col < C) ? f2bf(W[(size_t)(kbase + j) * C + col]) : 0u;
    uint4 o;
    o.x = v[0] | (v[1] << 16);
    o.y = v[2] | (v[3] << 16);
    o.z = v[4] | (v[5] << 16);
    o.w = v[6] | (v[7] << 16);
    ((uint4*)Wf)[t] = o;
}

// ===================== scatter edges into fixed buckets =====================
__global__ __launch_bounds__(256) void k_bscatter(const int* __restrict__ ei,
                                                  int* __restrict__ bcur,
                                                  unsigned int* __restrict__ ebuf,
                                                  int E, int NB) {
    __shared__ int h[768];
    __shared__ int wb[768];
    for (int i = threadIdx.x; i < 768; i += 256) h[i] = 0;
    __syncthreads();
    int base = blockIdx.x * 8192;
    int rk[32];
    #pragma unroll
    for (int it = 0; it < 32; ++it) {
        int e = base + it * 256 + threadIdx.x;
        rk[it] = (e < E) ? atomicAdd(&h[ei[E + e] >> 8], 1) : 0;
    }
    __syncthreads();
    for (int i = threadIdx.x; i < NB; i += 256) {
        int c = h[i];
        wb[i] = c ? atomicAdd(&bcur[i], c) : 0;
    }
    __syncthreads();
    #pragma unroll
    for (int it = 0; it < 32; ++it) {
        int e = base + it * 256 + threadIdx.x;
        if (e < E) {
            unsigned s = (unsigned)ei[e], d = (unsigned)ei[E + e];
            int bk = (int)(d >> 8);
            int pos = wb[bk] + rk[it];
            if (pos >= bk * CAP && pos < (bk + 1) * CAP)   // two-sided guard
                ebuf[pos] = s | ((d & 255u) << 24);
        }
    }
}

// ============ dispatch 3: CSR finalize || layer-0 GEMM (independent) ========
// blocks [0,NB): bfinal role (consumes ebuf/bcur from dispatch 2).
// blocks [NB, NB+gemm_grid): gemm0 role (consumes Wf from dispatch 1 + x).
// No intra-dispatch producer-consumer: race-free.
__global__ __launch_bounds__(256) void k_final_gemm0(
        const unsigned int* __restrict__ ebuf, const int* __restrict__ bcur,
        int* __restrict__ csr, int* __restrict__ rs, int* __restrict__ re,
        float* __restrict__ dinv,
        const float* __restrict__ X, const unsigned short* __restrict__ Wf,
        unsigned short* __restrict__ H, int N, int NB) {
    __shared__ int cnt[256];
    __shared__ int scn[256];
    __shared__ int cur[256];
    __shared__ unsigned short bF[8 * 4 * 512];
    const int t = threadIdx.x;
    if (blockIdx.x < (unsigned)NB) {
        // ---- bfinal role ----
        const int b = blockIdx.x;
        const int beg = b * CAP;
        const int cntE = min(bcur[b] - beg, CAP);
        cnt[t] = 0;
        __syncthreads();
        for (int j = t; j < cntE; j += 256)
            atomicAdd(&cnt[ebuf[beg + j] >> 24], 1);
        __syncthreads();
        int v = cnt[t];
        scn[t] = v;
        __syncthreads();
        for (int off = 1; off < 256; off <<= 1) {
            int x = (t >= off) ? scn[t - off] : 0;
            __syncthreads();
            scn[t] += x;
            __syncthreads();
        }
        int excl = scn[t] - v;
        int node = b * 256 + t;
        if (node < N) {
            rs[node]   = beg + excl;
            re[node]   = beg + excl + v;
            dinv[node] = rsqrtf((float)(1 + v));   // +1 self-loop
        }
        cur[t] = beg + excl;
        __syncthreads();
        for (int j = t; j < cntE; j += 256) {
            unsigned e = ebuf[beg + j];
            int pos = atomicAdd(&cur[e >> 24], 1);
            csr[pos] = (int)(e & 0x00FFFFFFu);
        }
        return;
    }
    // ---- gemm0 role: H[N,128] = bf16(X[N,128]_f32 @ W0) ----
    const int rowbase = (blockIdx.x - NB) * 64;
    {   // stage B: 8 col-tiles
        const uint4* src = (const uint4*)Wf;
        uint4* dst = (uint4*)bF;
        #pragma unroll
        for (int i = 0; i < 8; ++i) dst[t + 256 * i] = src[t + 256 * i];
    }
    __syncthreads();

    const int wave = t >> 6, lane = t & 63;
    const int r = lane & 15, q = lane >> 4;
    const int row  = rowbase + wave * 16 + r;
    const int rowc = min(row, N - 1);          // clamp: OOB rows computed, not stored

    bf16x8 afr[4];
    #pragma unroll
    for (int kt = 0; kt < 4; ++kt) {
        const int kc = kt * 32 + q * 8;
        const float4* xp = (const float4*)(X + (size_t)rowc * 128 + kc);
        float4 p0 = xp[0], p1 = xp[1];
        union { unsigned int u[4]; bf16x8 v; } pk;
        pk.u[0] = f2bf2(p0.x, p0.y);
        pk.u[1] = f2bf2(p0.z, p0.w);
        pk.u[2] = f2bf2(p1.x, p1.y);
        pk.u[3] = f2bf2(p1.z, p1.w);
        afr[kt] = pk.v;
    }

    f32x4 acc[8];
    #pragma unroll
    for (int ct = 0; ct < 8; ++ct) acc[ct] = (f32x4){0.f, 0.f, 0.f, 0.f};
    #pragma unroll
    for (int kt = 0; kt < 4; ++kt) {
        #pragma unroll
        for (int ct = 0; ct < 8; ++ct) {
            bf16x8 b = ((const bf16x8*)bF)[(ct * 4 + kt) * 64 + lane];
            acc[ct] = __builtin_amdgcn_mfma_f32_16x16x32_bf16(afr[kt], b, acc[ct], 0, 0, 0);
        }
    }
    #pragma unroll
    for (int ct = 0; ct < 8; ++ct) {
        #pragma unroll
        for (int i = 0; i < 4; i += 2) {
            int row0 = rowbase + wave * 16 + q * 4 + i;
            unsigned int pk = f2bf2(acc[ct][i], acc[ct][i + 1]);
            if (row0 < N)
                H[(size_t)row0 * 128 + ct * 16 + r] = (unsigned short)pk;
            if (row0 + 1 < N)
                H[(size_t)(row0 + 1) * 128 + ct * 16 + r] = (unsigned short)(pk >> 16);
        }
    }
}

// ============================== MFMA GEMM (layers 1,2) ======================
// No A-LDS: each wave loads its own 16x128 A-tile directly from global in
// MFMA fragment order. BN scale/shift precomputed once per block into LDS
// (stats summed over the 8 contention slabs written by fused agg128).
template <int NOCT, int OST>
__global__ __launch_bounds__(256) void k_gemm_mfma(
        const unsigned short* __restrict__ X, const unsigned short* __restrict__ Wf,
        unsigned short* __restrict__ H, int N,
        const float* __restrict__ stats, const float* __restrict__ g,
        const float* __restrict__ be) {
    __shared__ unsigned short bF[NOCT * 4 * 512];
    __shared__ float2 bnss[128];
    const int tid = threadIdx.x;
    const int rowbase = blockIdx.x * 64;

    if (tid < 128) {
        const float invN = 1.0f / (float)N;
        float se = 0.f, sq = 0.f;
        #pragma unroll
        for (int s = 0; s < 8; ++s) {
            se += stats[s * 256 + tid];
            sq += stats[s * 256 + 128 + tid];
        }
        float mean = se * invN;
        float var  = fmaf(-mean, mean, sq * invN);
        float sc   = g[tid] * rsqrtf(var + BN_EPS);
        bnss[tid]  = make_float2(sc, fmaf(-mean, sc, be[tid]));
    }
    {   // stage B: NOCT col-tiles, lane-contiguous copy
        const uint4* src = (const uint4*)Wf;
        uint4* dst = (uint4*)bF;
        #pragma unroll
        for (int i = 0; i < NOCT; ++i) dst[tid + 256 * i] = src[tid + 256 * i];
    }
    __syncthreads();   // bF + bnss ready

    const int wave = tid >> 6, lane = tid & 63;
    const int r = lane & 15, q = lane >> 4;
    const int row  = rowbase + wave * 16 + r;
    const int rowc = min(row, N - 1);          // clamp: OOB rows computed, not stored

    bf16x8 afr[4];
    #pragma unroll
    for (int kt = 0; kt < 4; ++kt) {
        const int kc = kt * 32 + q * 8;
        uint4 p = *((const uint4*)(X + (size_t)rowc * 128 + kc));
        float vv[8];
        vv[0] = bflo(p.x); vv[1] = bfhi(p.x);
        vv[2] = bflo(p.y); vv[3] = bfhi(p.y);
        vv[4] = bflo(p.z); vv[5] = bfhi(p.z);
        vv[6] = bflo(p.w); vv[7] = bfhi(p.w);
        #pragma unroll
        for (int j = 0; j < 8; ++j) {
            float2 ss = bnss[kc + j];
            vv[j] = fmaxf(fmaf(vv[j], ss.x, ss.y), 0.0f);
        }
        union { unsigned int u[4]; bf16x8 v; } pk;
        pk.u[0] = f2bf2(vv[0], vv[1]);
        pk.u[1] = f2bf2(vv[2], vv[3]);
        pk.u[2] = f2bf2(vv[4], vv[5]);
        pk.u[3] = f2bf2(vv[6], vv[7]);
        afr[kt] = pk.v;
    }

    f32x4 acc[NOCT];
    #pragma unroll
    for (int ct = 0; ct < NOCT; ++ct) acc[ct] = (f32x4){0.f, 0.f, 0.f, 0.f};

    #pragma unroll
    for (int kt = 0; kt < 4; ++kt) {
        #pragma unroll
        for (int ct = 0; ct < NOCT; ++ct) {
            bf16x8 b = ((const bf16x8*)bF)[(ct * 4 + kt) * 64 + lane];
            acc[ct] = __builtin_amdgcn_mfma_f32_16x16x32_bf16(afr[kt], b, acc[ct], 0, 0, 0);
        }
    }

    // C/D: col = ct*16 + r, row = q*4 + i; pack row-pairs, split halves
    #pragma unroll
    for (int ct = 0; ct < NOCT; ++ct) {
        #pragma unroll
        for (int i = 0; i < 4; i += 2) {
            int row0 = rowbase + wave * 16 + q * 4 + i;
            unsigned int pk = f2bf2(acc[ct][i], acc[ct][i + 1]);
            if (row0 < N)
                H[(size_t)row0 * OST + ct * 16 + r] = (unsigned short)pk;
            if (row0 + 1 < N)
                H[(size_t)(row0 + 1) * OST + ct * 16 + r] = (unsigned short)(pk >> 16);
        }
    }
}

// ================ gather-based aggregate + fused BN stats ===================
// 16 lanes/node, uint4 (8ch) per lane — proven roofline form, block structure
// UNCHANGED. Appended: each thread's node-partials (a_k, a_k^2) -> 16KB LDS
// reduce -> one atomic/thread into 8 slabs (blockIdx&7) to split contention.
// Replaces the separate k_bnstats dispatch.
__global__ __launch_bounds__(256) void k_agg128(
        const unsigned short* __restrict__ H, const int* __restrict__ rs,
        const int* __restrict__ re, const int* __restrict__ csr,
        const float* __restrict__ dinv, const float* __restrict__ b,
        unsigned short* __restrict__ outb, float* __restrict__ stats, int N) {
    __shared__ float red[2][16][128];
    const int t = threadIdx.x;
    int lane = t & 15;
    int node = blockIdx.x * 16 + (t >> 4);
    const bool valid = node < N;
    const int nodec = valid ? node : 0;
    float dd  = dinv[nodec];
    int   beg = rs[nodec];
    int   end = valid ? re[nodec] : beg;   // invalid -> empty edge loop
    uint4 hp  = ((const uint4*)(H + (size_t)nodec * 128))[lane];
    float4 bb0 = ((const float4*)b)[lane * 2];
    float4 bb1 = ((const float4*)b)[lane * 2 + 1];
    float sl = dd * dd;
    float a0 = fmaf(bflo(hp.x), sl, bb0.x), a1 = fmaf(bfhi(hp.x), sl, bb0.y);
    float a2 = fmaf(bflo(hp.y), sl, bb0.z), a3 = fmaf(bfhi(hp.y), sl, bb0.w);
    float a4 = fmaf(bflo(hp.z), sl, bb1.x), a5 = fmaf(bfhi(hp.z), sl, bb1.y);
    float a6 = fmaf(bflo(hp.w), sl, bb1.z), a7 = fmaf(bfhi(hp.w), sl, bb1.w);
    int j = beg;
    for (; j + 2 <= end; j += 2) {
        int s0 = csr[j], s1 = csr[j + 1];
        float n0 = dinv[s0] * dd, n1 = dinv[s1] * dd;
        uint4 v0 = ((const uint4*)(H + (size_t)s0 * 128))[lane];
        uint4 v1 = ((const uint4*)(H + (size_t)s1 * 128))[lane];
        a0 = fmaf(bflo(v0.x), n0, fmaf(bflo(v1.x), n1, a0));
        a1 = fmaf(bfhi(v0.x), n0, fmaf(bfhi(v1.x), n1, a1));
        a2 = fmaf(bflo(v0.y), n0, fmaf(bflo(v1.y), n1, a2));
        a3 = fmaf(bfhi(v0.y), n0, fmaf(bfhi(v1.y), n1, a3));
        a4 = fmaf(bflo(v0.z), n0, fmaf(bflo(v1.z), n1, a4));
        a5 = fmaf(bfhi(v0.z), n0, fmaf(bfhi(v1.z), n1, a5));
        a6 = fmaf(bflo(v0.w), n0, fmaf(bflo(v1.w), n1, a6));
        a7 = fmaf(bfhi(v0.w), n0, fmaf(bfhi(v1.w), n1, a7));
    }
    if (j < end) {
        int s0 = csr[j];
        float n0 = dinv[s0] * dd;
        uint4 v0 = ((const uint4*)(H + (size_t)s0 * 128))[lane];
        a0 = fmaf(bflo(v0.x), n0, a0); a1 = fmaf(bfhi(v0.x), n0, a1);
        a2 = fmaf(bflo(v0.y), n0, a2); a3 = fmaf(bfhi(v0.y), n0, a3);
        a4 = fmaf(bflo(v0.z), n0, a4); a5 = fmaf(bfhi(v0.z), n0, a5);
        a6 = fmaf(bflo(v0.w), n0, a6); a7 = fmaf(bfhi(v0.w), n0, a7);
    }
    if (valid) {
        uint4 o;
        o.x = f2bf2(a0, a1);
        o.y = f2bf2(a2, a3);
        o.z = f2bf2(a4, a5);
        o.w = f2bf2(a6, a7);
        ((uint4*)(outb + (size_t)node * 128))[lane] = o;
    } else {
        a0 = a1 = a2 = a3 = a4 = a5 = a6 = a7 = 0.f;
    }
    // ---- fused BN stats: per-node partials -> LDS -> slab atomics ----
    const int grp = t >> 4, cb = lane * 8;
    red[0][grp][cb + 0] = a0; red[1][grp][cb + 0] = a0 * a0;
    red[0][grp][cb + 1] = a1; red[1][grp][cb + 1] = a1 * a1;
    red[0][grp][cb + 2] = a2; red[1][grp][cb + 2] = a2 * a2;
    red[0][grp][cb + 3] = a3; red[1][grp][cb + 3] = a3 * a3;
    red[0][grp][cb + 4] = a4; red[1][grp][cb + 4] = a4 * a4;
    red[0][grp][cb + 5] = a5; red[1][grp][cb + 5] = a5 * a5;
    red[0][grp][cb + 6] = a6; red[1][grp][cb + 6] = a6 * a6;
    red[0][grp][cb + 7] = a7; red[1][grp][cb + 7] = a7 * a7;
    __syncthreads();
    const int slab = blockIdx.x & 7;
    const int rot  = (blockIdx.x >> 3) << 2;   // stagger channel order
    if (t < 128) {
        int c = (t + rot) & 127;
        float acc = 0.f;
        #pragma unroll
        for (int g = 0; g < 16; ++g) acc += red[0][g][c];
        unsafeAtomicAdd(&stats[slab * 256 + c], acc);
    } else {
        int c = ((t - 128) + rot) & 127;
        float acc = 0.f;
        #pragma unroll
        for (int g = 0; g < 16; ++g) acc += red[1][g][c];
        unsafeAtomicAdd(&stats[slab * 256 + 128 + c], acc);
    }
}

// 40-ch final from line-aligned stride-64 H (1 cache line per gathered row)
__global__ __launch_bounds__(256) void k_agg40(
        const unsigned short* __restrict__ H, const int* __restrict__ rs,
        const int* __restrict__ re, const int* __restrict__ csr,
        const float* __restrict__ dinv, const float* __restrict__ b,
        float* __restrict__ out, int N) {
    int lane = threadIdx.x & 15;
    int node = blockIdx.x * 16 + (threadIdx.x >> 4);
    if (node >= N || lane >= 10) return;
    float dd  = dinv[node];
    int   beg = rs[node];
    int   end = re[node];
    uint2 hp  = ((const uint2*)(H + (size_t)node * 64))[lane];
    float4 bb = ((const float4*)b)[lane];
    float  sl = dd * dd;
    float4 acc = make_float4(fmaf(bflo(hp.x), sl, bb.x), fmaf(bfhi(hp.x), sl, bb.y),
                             fmaf(bflo(hp.y), sl, bb.z), fmaf(bfhi(hp.y), sl, bb.w));
    int j = beg;
    for (; j + 2 <= end; j += 2) {
        int s0 = csr[j], s1 = csr[j + 1];
        float n0 = dinv[s0] * dd, n1 = dinv[s1] * dd;
        uint2 v0 = ((const uint2*)(H + (size_t)s0 * 64))[lane];
        uint2 v1 = ((const uint2*)(H + (size_t)s1 * 64))[lane];
        acc.x = fmaf(bflo(v0.x), n0, fmaf(bflo(v1.x), n1, acc.x));
        acc.y = fmaf(bfhi(v0.x), n0, fmaf(bfhi(v1.x), n1, acc.y));
        acc.z = fmaf(bflo(v0.y), n0, fmaf(bflo(v1.y), n1, acc.z));
        acc.w = fmaf(bfhi(v0.y), n0, fmaf(bfhi(v1.y), n1, acc.w));
    }
    if (j < end) {
        int s0 = csr[j];
        float n0 = dinv[s0] * dd;
        uint2 v0 = ((const uint2*)(H + (size_t)s0 * 64))[lane];
        acc.x = fmaf(bflo(v0.x), n0, acc.x);
        acc.y = fmaf(bfhi(v0.x), n0, acc.y);
        acc.z = fmaf(bflo(v0.y), n0, acc.z);
        acc.w = fmaf(bfhi(v0.y), n0, acc.w);
    }
    ((float4*)(out + (size_t)node * 40))[lane] = acc;
}

// ================================ launch ====================================
extern "C" void kernel_launch(void* const* d_in, const int* in_sizes, int n_in,
                              void* d_out, int out_size, void* d_ws, size_t ws_size,
                              hipStream_t stream) {
    const float* x   = (const float*)d_in[0];
    const int*   ei  = (const int*)d_in[1];      // int64 in ref -> int32 from harness
    const float* W0  = (const float*)d_in[2];
    const float* b0  = (const float*)d_in[3];
    const float* g0  = (const float*)d_in[4];
    const float* be0 = (const float*)d_in[5];
    const float* W1  = (const float*)d_in[6];
    const float* b1  = (const float*)d_in[7];
    const float* g1  = (const float*)d_in[8];
    const float* be1 = (const float*)d_in[9];
    const float* W2  = (const float*)d_in[10];
    const float* b2  = (const float*)d_in[11];
    float* out = (float*)d_out;

    const int N  = in_sizes[0] / 128;   // 170000
    const int E  = in_sizes[1] / 2;     // 1200000
    const int NB = (N + 255) >> 8;      // 665 buckets
    const int EB = (E + 8191) / 8192;   // 147 edge-chunk blocks

    // ws layout (4B units)
    float* ws   = (float*)d_ws;
    size_t Npad = ((size_t)N + 511) & ~(size_t)511;
    size_t BCAP = (size_t)NB * CAP;
    float* dinv = ws;
    int*   rs   = (int*)(ws + Npad);
    int*   re   = rs + Npad;
    int*   csr  = re + Npad;                            // BCAP
    unsigned int* ebuf = (unsigned int*)(csr + BCAP);   // BCAP
    int*   bcur = (int*)(ebuf + BCAP);                  // 1024
    float* stats0 = (float*)(bcur + 1024);              // 8 slabs x 256
    float* stats1 = stats0 + 2048;                      // 8 slabs x 256
    unsigned short* Wf = (unsigned short*)(stats1 + 2048); // 3*16384 ushort
    unsigned short* Hb = Wf + 3 * 16384;                // Npad*128 bf16
    unsigned short* Bb = Hb + Npad * 128;               // Npad*128 bf16

    int gemm_grid = (N + 63) / 64;
    int agg_grid  = (N + 15) / 16;

    // ---- dispatch 1: Wf prep + bcur/stats init (must precede bscatter) ----
    k_prepW3  <<<24, 256, 0, stream>>>(W0, W1, W2, Wf, bcur, stats0, NB);
    // ---- dispatch 2: edge scatter ----
    k_bscatter<<<EB, 256, 0, stream>>>(ei, bcur, ebuf, E, NB);
    // ---- dispatch 3: CSR finalize || layer-0 GEMM (independent roles) ----
    k_final_gemm0<<<NB + gemm_grid, 256, 0, stream>>>(ebuf, bcur, csr, rs, re,
                                                      dinv, x, Wf, Hb, N, NB);

    // ---- layer 0 aggregate (+ fused BN0 stats) ----
    k_agg128<<<agg_grid, 256, 0, stream>>>(Hb, rs, re, csr, dinv, b0, Bb,
                                           stats0, N);

    // ---- layer 1 (BN0+ReLU fused into GEMM staging); agg fuses BN1 stats ----
    k_gemm_mfma<8, 128><<<gemm_grid, 256, 0, stream>>>(Bb, Wf + 16384, Hb, N,
                                                       stats0, g0, be0);
    k_agg128<<<agg_grid, 256, 0, stream>>>(Hb, rs, re, csr, dinv, b1, Bb,
                                           stats1, N);

    // ---- layer 2 (BN1+ReLU fused) -> line-aligned 64-stride H -> 40-ch out ----
    k_gemm_mfma<3, 64><<<gemm_grid, 256, 0, stream>>>(Bb, Wf + 2 * 16384, Hb, N,
                                                      stats1, g1, be1);
    k_agg40<<<agg_grid, 256, 0, stream>>>(Hb, rs, re, csr, dinv, b2, out, N);
}